// Round 1
// baseline (2308.082 us; speedup 1.0000x reference)
//
#include <hip/hip_runtime.h>
#include <hip/hip_bf16.h>
#include <stdint.h>

// ---------------------------------------------------------------------------
// MolDis: 2x RelGraphConv(D=32, R=4) + ReLU, then per-32-row mean pool.
//   layer(h): agg[dst] += W[etype]^T h[src];  out = agg + h@W_loop + bias
// Strategy:
//   - bucket edges by etype once (reused by both layers) so edge kernel can
//     hold its W column-pair entirely in VGPRs (wave-uniform relation).
//   - 16 lanes per edge, 2 outputs per lane; full h row loaded per thread
//     (coalesces to 4 rows x 16B segments per dwordx4 instruction).
//   - scatter via global f32 atomicAdd into accumulator pre-initialized by
//     the self-loop kernel (bias + h@W_loop) -> no separate zeroing pass.
// ---------------------------------------------------------------------------

__global__ void init_kernel(int* cnt) {
    if (threadIdx.x < 4) cnt[threadIdx.x] = 0;
}

__global__ __launch_bounds__(1024) void hist_kernel(const int* __restrict__ etype, int E,
                                                    int* __restrict__ cnt) {
    __shared__ int h[4];
    if (threadIdx.x < 4) h[threadIdx.x] = 0;
    __syncthreads();
    int e = blockIdx.x * 1024 + threadIdx.x;
    if (e < E) atomicAdd(&h[etype[e] & 3], 1);
    __syncthreads();
    if (threadIdx.x < 4) atomicAdd(&cnt[threadIdx.x], h[threadIdx.x]);
}

__global__ void scan_kernel(const int* __restrict__ cnt, int* __restrict__ off,
                            int* __restrict__ alloc) {
    if (threadIdx.x == 0) {
        int s = 0;
        for (int r = 0; r < 4; ++r) { off[r] = s; alloc[r] = s; s += cnt[r]; }
    }
}

__global__ __launch_bounds__(1024) void scatter_kernel(const int* __restrict__ src,
                                                       const int* __restrict__ dst,
                                                       const int* __restrict__ etype, int E,
                                                       int* __restrict__ alloc,
                                                       int2* __restrict__ bsd) {
    __shared__ int h[4], base[4], pos[4];
    if (threadIdx.x < 4) { h[threadIdx.x] = 0; pos[threadIdx.x] = 0; }
    __syncthreads();
    int e = blockIdx.x * 1024 + threadIdx.x;
    int et = 0;
    bool valid = (e < E);
    if (valid) { et = etype[e] & 3; atomicAdd(&h[et], 1); }
    __syncthreads();
    if (threadIdx.x < 4) base[threadIdx.x] = atomicAdd(&alloc[threadIdx.x], h[threadIdx.x]);
    __syncthreads();
    if (valid) {
        int p = atomicAdd(&pos[et], 1);
        bsd[base[et] + p] = make_int2(src[e], dst[e]);
    }
}

// out[n][co..co+1] = bias + act(h[n]) @ W_loop  (also serves as accumulator init)
template<bool RELU>
__global__ __launch_bounds__(256) void selfloop_kernel(const float* __restrict__ h,
                                                       const float* __restrict__ Wl,
                                                       const float* __restrict__ bias,
                                                       float* __restrict__ outb, int N) {
    const int co = (threadIdx.x & 15) * 2;
    float2 w[32];
#pragma unroll
    for (int i = 0; i < 32; ++i) w[i] = *(const float2*)(Wl + i * 32 + co);
    const float2 b = *(const float2*)(bias + co);
    int node = (blockIdx.x * 256 + threadIdx.x) >> 4;
    const int stride = (gridDim.x * 256) >> 4;
    for (; node < N; node += stride) {
        const float4* hp = (const float4*)(h + (size_t)node * 32);
        float4 hv[8];
#pragma unroll
        for (int j = 0; j < 8; ++j) {
            float4 v = hp[j];
            if (RELU) {
                v.x = fmaxf(v.x, 0.f); v.y = fmaxf(v.y, 0.f);
                v.z = fmaxf(v.z, 0.f); v.w = fmaxf(v.w, 0.f);
            }
            hv[j] = v;
        }
        float a0 = b.x, a1 = b.y;
#pragma unroll
        for (int j = 0; j < 8; ++j) {
            a0 = fmaf(hv[j].x, w[4*j+0].x, a0); a1 = fmaf(hv[j].x, w[4*j+0].y, a1);
            a0 = fmaf(hv[j].y, w[4*j+1].x, a0); a1 = fmaf(hv[j].y, w[4*j+1].y, a1);
            a0 = fmaf(hv[j].z, w[4*j+2].x, a0); a1 = fmaf(hv[j].z, w[4*j+2].y, a1);
            a0 = fmaf(hv[j].w, w[4*j+3].x, a0); a1 = fmaf(hv[j].w, w[4*j+3].y, a1);
        }
        *(float2*)(outb + (size_t)node * 32 + co) = make_float2(a0, a1);
    }
}

// agg[dst] += W[r]^T act(h[src]) over bucket r; blockIdx&3 selects relation.
template<bool RELU>
__global__ __launch_bounds__(256) void edge_kernel(const float* __restrict__ h,
                                                   const float* __restrict__ W,
                                                   const int2* __restrict__ bsd,
                                                   const int* __restrict__ off,
                                                   const int* __restrict__ cnt,
                                                   float* __restrict__ agg) {
    const int r   = blockIdx.x & 3;
    const int sub = blockIdx.x >> 2;
    const int co  = (threadIdx.x & 15) * 2;
    const float* Wr = W + r * 1024;
    float2 w[32];
#pragma unroll
    for (int i = 0; i < 32; ++i) w[i] = *(const float2*)(Wr + i * 32 + co);
    const int n    = cnt[r];
    const int base = off[r];
    const int stride = (gridDim.x >> 2) * (256 / 16);
    int i = sub * (256 / 16) + (threadIdx.x >> 4);
    for (; i < n; i += stride) {
        const int2 sd = bsd[base + i];
        const float4* hp = (const float4*)(h + (size_t)sd.x * 32);
        float4 hv[8];
#pragma unroll
        for (int j = 0; j < 8; ++j) {
            float4 v = hp[j];
            if (RELU) {
                v.x = fmaxf(v.x, 0.f); v.y = fmaxf(v.y, 0.f);
                v.z = fmaxf(v.z, 0.f); v.w = fmaxf(v.w, 0.f);
            }
            hv[j] = v;
        }
        float a0 = 0.f, a1 = 0.f;
#pragma unroll
        for (int j = 0; j < 8; ++j) {
            a0 = fmaf(hv[j].x, w[4*j+0].x, a0); a1 = fmaf(hv[j].x, w[4*j+0].y, a1);
            a0 = fmaf(hv[j].y, w[4*j+1].x, a0); a1 = fmaf(hv[j].y, w[4*j+1].y, a1);
            a0 = fmaf(hv[j].z, w[4*j+2].x, a0); a1 = fmaf(hv[j].z, w[4*j+2].y, a1);
            a0 = fmaf(hv[j].w, w[4*j+3].x, a0); a1 = fmaf(hv[j].w, w[4*j+3].y, a1);
        }
        float* outp = agg + (size_t)sd.y * 32 + co;
        atomicAdd(outp,     a0);
        atomicAdd(outp + 1, a1);
    }
}

// out[m][o] = mean_a relu(pre2[m*32+a][o])
__global__ __launch_bounds__(256) void pool_kernel(const float* __restrict__ pre2,
                                                   float* __restrict__ out, int total) {
    int t = blockIdx.x * 256 + threadIdx.x;
    if (t >= total) return;
    const int m = t >> 5, o = t & 31;
    const float* p = pre2 + (size_t)m * 1024 + o;
    float s = 0.f;
#pragma unroll
    for (int a = 0; a < 32; ++a) s += fmaxf(p[a * 32], 0.f);
    out[t] = s * (1.0f / 32.0f);
}

extern "C" void kernel_launch(void* const* d_in, const int* in_sizes, int n_in,
                              void* d_out, int out_size, void* d_ws, size_t ws_size,
                              hipStream_t stream) {
    const float* x     = (const float*)d_in[0];
    const float* W     = (const float*)d_in[1];
    const float* Wl    = (const float*)d_in[2];
    const float* bias  = (const float*)d_in[3];
    const int*   src   = (const int*)d_in[4];
    const int*   dst   = (const int*)d_in[5];
    const int*   etype = (const int*)d_in[6];

    const int N = in_sizes[0] / 32;   // 1048576
    const int E = in_sizes[4];        // 4194304
    const int M = N / 32;             // 32768 molecules

    char* ws = (char*)d_ws;
    float* agg1  = (float*)ws;                                    // N*32 f32 (128 MB)
    float* agg2  = (float*)(ws + (size_t)N * 32 * 4);             // N*32 f32 (128 MB)
    int2*  bsd   = (int2*)(ws + (size_t)N * 32 * 4 * 2);          // E int2  (32 MB)
    int*   cnt   = (int*)(ws + (size_t)N * 32 * 4 * 2 + (size_t)E * 8);
    int*   off   = cnt + 4;
    int*   alloc = cnt + 8;

    const int hb = (E + 1023) / 1024;

    // ---- build etype buckets (graph is static across both layers) ----
    init_kernel<<<1, 64, 0, stream>>>(cnt);
    hist_kernel<<<hb, 1024, 0, stream>>>(etype, E, cnt);
    scan_kernel<<<1, 64, 0, stream>>>(cnt, off, alloc);
    scatter_kernel<<<hb, 1024, 0, stream>>>(src, dst, etype, E, alloc, bsd);

    // ---- layer 1: input x (no activation on input) ----
    selfloop_kernel<false><<<8192, 256, 0, stream>>>(x, Wl, bias, agg1, N);
    edge_kernel<false><<<8192, 256, 0, stream>>>(x, W, bsd, off, cnt, agg1);

    // ---- layer 2: input relu(agg1), applied on the fly ----
    selfloop_kernel<true><<<8192, 256, 0, stream>>>(agg1, Wl, bias, agg2, N);
    edge_kernel<true><<<8192, 256, 0, stream>>>(agg1, W, bsd, off, cnt, agg2);

    // ---- molecule mean pool of relu(agg2) ----
    pool_kernel<<<(M * 32 + 255) / 256, 256, 0, stream>>>(agg2, (float*)d_out, M * 32);
}